// Round 1
// baseline (210.145 us; speedup 1.0000x reference)
//
#include <hip/hip_runtime.h>
#include <math.h>

#define FDIM 512
#define TILE 8                  // rows per wave
#define WPB  4                  // waves per block
#define SPB  (TILE * WPB)       // 32 rows per block

#define RYPAIR(x, y, c, s) { float n0_ = (c)*(x) - (s)*(y); float n1_ = (s)*(x) + (c)*(y); (x) = n0_; (y) = n1_; }
#define SWAPF(x, y) { float t_ = (x); (x) = (y); (y) = t_; }

// Merge-reduce two accumulators across lane-xor `mask`:
//   lanes with (lane&mask)==0 continue carrying x's reduction,
//   lanes with (lane&mask)!=0 continue carrying y's reduction.
// After the merge, x holds (own value + partner-lane value) of the carried accumulator.
#define MERGE(x, y, mask) {                       \
    const bool hi_ = (lane & (mask));             \
    float keep_ = hi_ ? (y) : (x);                \
    float send_ = hi_ ? (x) : (y);                \
    (x) = keep_ + __shfl_xor(send_, (mask)); }

__global__ __launch_bounds__(256) void qnet_v3(
    const float4* __restrict__ in4,      // [B,512] f32, 128 float4 per row
    const float4* __restrict__ preW4,    // [3,512] f32 as 384 float4
    const float*  __restrict__ preb,     // [3] f32
    const float*  __restrict__ qp,       // [45] f32
    const float*  __restrict__ postW,    // [100,3] f32
    const float*  __restrict__ postb,    // [100] f32
    float2*       __restrict__ out,      // [B,100] f32 as [B,50] float2
    int B)
{
    const int tid  = threadIdx.x;
    const int lane = tid & 63;
    const int wave = tid >> 6;

    // ---- pre_W entirely in registers: lane l holds features {4l..4l+3} (a)
    //      and {256+4l..256+4l+3} (b) of each of the 3 W rows. 24 VGPRs. ----
    const float4 w0a = preW4[lane],       w0b = preW4[64 + lane];
    const float4 w1a = preW4[128 + lane], w1b = preW4[192 + lane];
    const float4 w2a = preW4[256 + lane], w2b = preW4[320 + lane];

    const float pb0 = preb[0], pb1 = preb[1], pb2 = preb[2];

    float cw[2][3], sw[2][3];              // shared-weight RY half-angles (qw rows 1..2)
    #pragma unroll
    for (int k = 0; k < 2; ++k)
        #pragma unroll
        for (int j = 0; j < 3; ++j) {
            float th = 0.5f * qp[(k + 1) * 3 + j];
            sw[k][j] = sinf(th);
            cw[k][j] = cosf(th);
        }

    // epilogue weights: lane l (<50) produces outputs o=2l, 2l+1
    const int ol = (lane < 50) ? lane : 49;
    const float* pw = postW + 6 * ol;
    const float w00 = pw[0], w01 = pw[1], w02 = pw[2];
    const float w10 = pw[3], w11 = pw[4], w12 = pw[5];
    const float b0 = postb[2 * ol], b1 = postb[2 * ol + 1];

    const int tile_base = blockIdx.x * SPB + wave * TILE;

    // ---- Phase A1: pure load+FMA loop, no cross-lane ops. Each iteration is
    //      two contiguous 1KB wave-loads + 24 FMAs; the compiler can pipeline
    //      all 16 loads since nothing serializes them. ----
    float a[TILE][3];
    #pragma unroll
    for (int s = 0; s < TILE; ++s) {
        int row = tile_base + s;
        if (row >= B) row = B - 1;
        const float4* rp = in4 + (size_t)row * 128;
        float4 i0 = rp[lane];              // 64 lanes x 16B = 1KB contiguous
        float4 i1 = rp[64 + lane];         // second 1KB half of the row

        float a0 = fmaf(i0.w, w0a.w, fmaf(i0.z, w0a.z, fmaf(i0.y, w0a.y, i0.x * w0a.x)));
        a0 = fmaf(i1.w, w0b.w, fmaf(i1.z, w0b.z, fmaf(i1.y, w0b.y, fmaf(i1.x, w0b.x, a0))));
        float a1 = fmaf(i0.w, w1a.w, fmaf(i0.z, w1a.z, fmaf(i0.y, w1a.y, i0.x * w1a.x)));
        a1 = fmaf(i1.w, w1b.w, fmaf(i1.z, w1b.z, fmaf(i1.y, w1b.y, fmaf(i1.x, w1b.x, a1))));
        float a2 = fmaf(i0.w, w2a.w, fmaf(i0.z, w2a.z, fmaf(i0.y, w2a.y, i0.x * w2a.x)));
        a2 = fmaf(i1.w, w2b.w, fmaf(i1.z, w2b.z, fmaf(i1.y, w2b.y, fmaf(i1.x, w2b.x, a2))));

        a[s][0] = a0; a[s][1] = a1; a[s][2] = a2;
    }

    // ---- Phase A2: halving merge-reduction. 24 accumulators -> 3, in
    //      30 shfl total (vs 144 for per-row butterflies). Row index ends
    //      up encoded in lane bits [5:3]: lane l carries row (l>>3). ----
    #pragma unroll
    for (int s = 0; s < 4; ++s) {
        #pragma unroll
        for (int j = 0; j < 3; ++j) MERGE(a[s][j], a[s + 4][j], 32);
    }
    #pragma unroll
    for (int s = 0; s < 2; ++s) {
        #pragma unroll
        for (int j = 0; j < 3; ++j) MERGE(a[s][j], a[s + 2][j], 16);
    }
    #pragma unroll
    for (int j = 0; j < 3; ++j) MERGE(a[0][j], a[1][j], 8);
    // finish: sum across the 8 lanes of each row-group (lane bits 0..2)
    #pragma unroll
    for (int m = 4; m >= 1; m >>= 1) {
        #pragma unroll
        for (int j = 0; j < 3; ++j) a[0][j] += __shfl_xor(a[0][j], m);
    }

    // ---- Phase B: per-lane quantum circuit. Every lane holds the full
    //      (d0,d1,d2) of row (lane>>3); the 8 lanes per group are redundant. ----
    float d0 = a[0][0] + pb0;
    float d1 = a[0][1] + pb1;
    float d2 = a[0][2] + pb2;

    // q_in = tanh(d)*pi/2 ; RY half-angle = tanh(d)*pi/4
    float t0 = tanhf(d0) * 0.785398163397448f;
    float t1 = tanhf(d1) * 0.785398163397448f;
    float t2 = tanhf(d2) * 0.785398163397448f;
    float s0 = sinf(t0), c0 = cosf(t0);
    float s1 = sinf(t1), c1 = cosf(t1);
    float s2 = sinf(t2), c2 = cosf(t2);

    // product state after H-layer + per-sample RYs: amp(b0b1b2) = prod (c_j -/+ s_j) / sqrt(8)
    const float r8 = 0.353553390593274f;
    float u0m = c0 - s0, u0p = c0 + s0;
    float u1m = c1 - s1, u1p = c1 + s1;
    float u2m = (c2 - s2) * r8, u2p = (c2 + s2) * r8;
    float t00 = u0m * u1m, t01 = u0m * u1p, t10 = u0p * u1m, t11 = u0p * u1p;
    float q0 = t00 * u2m, q1 = t00 * u2p;   // idx = 4*b0 + 2*b1 + b2
    float q2 = t01 * u2m, q3 = t01 * u2p;
    float q4 = t10 * u2m, q5 = t10 * u2p;
    float q6 = t11 * u2m, q7 = t11 * u2p;

    #pragma unroll
    for (int k = 0; k < 2; ++k) {
        SWAPF(q4, q6); SWAPF(q5, q7);       // CNOT(q0 -> q1)
        SWAPF(q2, q3); SWAPF(q6, q7);       // CNOT(q1 -> q2)
        float c = cw[k][0], s = sw[k][0];   // RY qubit 0: pairs (i, i+4)
        RYPAIR(q0, q4, c, s); RYPAIR(q1, q5, c, s); RYPAIR(q2, q6, c, s); RYPAIR(q3, q7, c, s);
        c = cw[k][1]; s = sw[k][1];         // RY qubit 1: pairs (i, i+2)
        RYPAIR(q0, q2, c, s); RYPAIR(q1, q3, c, s); RYPAIR(q4, q6, c, s); RYPAIR(q5, q7, c, s);
        c = cw[k][2]; s = sw[k][2];         // RY qubit 2: pairs (i, i+1)
        RYPAIR(q0, q1, c, s); RYPAIR(q2, q3, c, s); RYPAIR(q4, q5, c, s); RYPAIR(q6, q7, c, s);
    }

    float p0 = q0 * q0, p1 = q1 * q1, p2 = q2 * q2, p3 = q3 * q3;
    float p4 = q4 * q4, p5 = q5 * q5, p6 = q6 * q6, p7 = q7 * q7;
    float s01 = p0 + p1, s23 = p2 + p3, s45 = p4 + p5, s67 = p6 + p7;
    float z0 = (s01 + s23) - (s45 + s67);
    float z1 = (s01 - s23) + (s45 - s67);
    float z2 = (p0 - p1) + ((p2 - p3) + ((p4 - p5) + (p6 - p7)));

    // ---- Phase C: epilogue GEMM [*,3]x[3,100] + coalesced f32 stores.
    //      Row s lives in lanes [8s..8s+7]; __shfl with the constant lane 8s
    //      compiles to v_readlane (scalar broadcast). ----
    #pragma unroll
    for (int s = 0; s < TILE; ++s) {
        float zz0 = __shfl(z0, 8 * s);
        float zz1 = __shfl(z1, 8 * s);
        float zz2 = __shfl(z2, 8 * s);
        int row = tile_base + s;
        float v0 = fmaf(zz2, w02, fmaf(zz1, w01, fmaf(zz0, w00, b0)));
        float v1 = fmaf(zz2, w12, fmaf(zz1, w11, fmaf(zz0, w10, b1)));
        if (lane < 50 && row < B) {
            float2 st; st.x = v0; st.y = v1;
            out[(size_t)row * 50 + lane] = st;   // 50 lanes x 8B = 400B/row contiguous
        }
    }
}

extern "C" void kernel_launch(void* const* d_in, const int* in_sizes, int n_in,
                              void* d_out, int out_size, void* d_ws, size_t ws_size,
                              hipStream_t stream) {
    const float4* in4   = (const float4*)d_in[0];
    const float4* preW4 = (const float4*)d_in[1];
    const float*  preb  = (const float*)d_in[2];
    const float*  qp    = (const float*)d_in[3];
    const float*  postW = (const float*)d_in[4];
    const float*  postb = (const float*)d_in[5];
    float2*       out   = (float2*)d_out;

    int B = in_sizes[0] / FDIM;                    // 65536
    int nblocks = (B + SPB - 1) / SPB;             // 2048
    qnet_v3<<<nblocks, 256, 0, stream>>>(in4, preW4, preb, qp, postW, postb, out, B);
}

// Round 3
// 199.890 us; speedup vs baseline: 1.0513x; 1.0513x over previous
//
#include <hip/hip_runtime.h>
#include <math.h>

#define FDIM 512
#define TILE 8                  // rows per wave
#define WPB  4                  // waves per block
#define SPB  (TILE * WPB)       // 32 rows per block
#define NBLK 1024               // persistent grid: 2 tiles per wave at B=65536

typedef float vf4 __attribute__((ext_vector_type(4)));   // nontemporal-builtin-compatible
typedef float vf2 __attribute__((ext_vector_type(2)));

#define RYPAIR(x, y, c, s) { float n0_ = (c)*(x) - (s)*(y); float n1_ = (s)*(x) + (c)*(y); (x) = n0_; (y) = n1_; }
#define SWAPF(x, y) { float t_ = (x); (x) = (y); (y) = t_; }

// Merge-reduce two accumulators across lane-xor `mask` (see R1 notes):
// lane keeps x's or y's reduction depending on (lane & mask); after log2 steps
// the row index lands in the high lane bits.
#define MERGE(x, y, mask) {                       \
    const bool hi_ = (lane & (mask));             \
    float keep_ = hi_ ? (y) : (x);                \
    float send_ = hi_ ? (x) : (y);                \
    (x) = keep_ + __shfl_xor(send_, (mask)); }

// __launch_bounds__(256,4): 4 waves/EU -> VGPR cap 128 -> 4 blocks/CU = 16 waves/CU.
__global__ __launch_bounds__(256, 4) void qnet_v4(
    const float4* __restrict__ in4,      // [B,512] f32, 128 float4 per row
    const float4* __restrict__ preW4,    // [3,512] f32 as 384 float4
    const float*  __restrict__ preb,     // [3] f32
    const float*  __restrict__ qp,       // [45] f32
    const float*  __restrict__ postW,    // [100,3] f32
    const float*  __restrict__ postb,    // [100] f32
    float2*       __restrict__ out,      // [B,100] f32 as [B,50] float2
    int B)
{
    const int tid  = threadIdx.x;
    const int lane = tid & 63;
    const int wave = tid >> 6;

    // ================= per-wave setup: amortized over ntiles =================
    // pre_W entirely in registers: lane l holds features {4l..4l+3} (a)
    // and {256+4l..256+4l+3} (b) of each of the 3 W rows. 24 VGPRs.
    const float4 w0a = preW4[lane],       w0b = preW4[64 + lane];
    const float4 w1a = preW4[128 + lane], w1b = preW4[192 + lane];
    const float4 w2a = preW4[256 + lane], w2b = preW4[320 + lane];

    const float pb0 = preb[0], pb1 = preb[1], pb2 = preb[2];

    float cw[2][3], sw[2][3];              // shared-weight RY half-angles (qw rows 1..2)
    #pragma unroll
    for (int k = 0; k < 2; ++k)
        #pragma unroll
        for (int j = 0; j < 3; ++j) {
            float th = 0.5f * qp[(k + 1) * 3 + j];
            sw[k][j] = sinf(th);
            cw[k][j] = cosf(th);
        }

    // epilogue weights: lane l (<50) produces outputs o=2l, 2l+1
    const int ol = (lane < 50) ? lane : 49;
    const float* pw = postW + 6 * ol;
    const float w00 = pw[0], w01 = pw[1], w02 = pw[2];
    const float w10 = pw[3], w11 = pw[4], w12 = pw[5];
    const float b0 = postb[2 * ol], b1 = postb[2 * ol + 1];

    const int tiles_per_grid = SPB * gridDim.x;
    const int ntiles = (B + tiles_per_grid - 1) / tiles_per_grid;

    // ======================= persistent tile loop =======================
    #pragma unroll 1
    for (int t = 0; t < ntiles; ++t) {
        const int tile_base = (blockIdx.x + t * gridDim.x) * SPB + wave * TILE;
        if (tile_base >= B) break;

        // ---- Phase A1: two 4-row load batches (8 float4 in flight each)
        //      keeps peak VGPR under the 128 cap; loads stay 1KB contiguous. ----
        float a[TILE][3];
        #pragma unroll
        for (int h = 0; h < 2; ++h) {
            vf4 i0v[4], i1v[4];
            #pragma unroll
            for (int s = 0; s < 4; ++s) {
                int row = tile_base + h * 4 + s;
                if (row >= B) row = B - 1;
                const vf4* rp = (const vf4*)(in4 + (size_t)row * 128);
                i0v[s] = __builtin_nontemporal_load(rp + lane);        // 1KB/wave
                i1v[s] = __builtin_nontemporal_load(rp + 64 + lane);   // 1KB/wave
            }
            #pragma unroll
            for (int s = 0; s < 4; ++s) {
                const vf4 i0 = i0v[s], i1 = i1v[s];
                float a0 = fmaf(i0.w, w0a.w, fmaf(i0.z, w0a.z, fmaf(i0.y, w0a.y, i0.x * w0a.x)));
                a0 = fmaf(i1.w, w0b.w, fmaf(i1.z, w0b.z, fmaf(i1.y, w0b.y, fmaf(i1.x, w0b.x, a0))));
                float a1 = fmaf(i0.w, w1a.w, fmaf(i0.z, w1a.z, fmaf(i0.y, w1a.y, i0.x * w1a.x)));
                a1 = fmaf(i1.w, w1b.w, fmaf(i1.z, w1b.z, fmaf(i1.y, w1b.y, fmaf(i1.x, w1b.x, a1))));
                float a2 = fmaf(i0.w, w2a.w, fmaf(i0.z, w2a.z, fmaf(i0.y, w2a.y, i0.x * w2a.x)));
                a2 = fmaf(i1.w, w2b.w, fmaf(i1.z, w2b.z, fmaf(i1.y, w2b.y, fmaf(i1.x, w2b.x, a2))));
                a[h * 4 + s][0] = a0; a[h * 4 + s][1] = a1; a[h * 4 + s][2] = a2;
            }
        }

        // ---- Phase A2: halving merge-reduction, 30 shfl total.
        //      Lane l ends carrying row (l>>3)'s full (d0,d1,d2). ----
        #pragma unroll
        for (int s = 0; s < 4; ++s) {
            #pragma unroll
            for (int j = 0; j < 3; ++j) MERGE(a[s][j], a[s + 4][j], 32);
        }
        #pragma unroll
        for (int s = 0; s < 2; ++s) {
            #pragma unroll
            for (int j = 0; j < 3; ++j) MERGE(a[s][j], a[s + 2][j], 16);
        }
        #pragma unroll
        for (int j = 0; j < 3; ++j) MERGE(a[0][j], a[1][j], 8);
        #pragma unroll
        for (int m = 4; m >= 1; m >>= 1) {
            #pragma unroll
            for (int j = 0; j < 3; ++j) a[0][j] += __shfl_xor(a[0][j], m);
        }

        // ---- Phase B: per-lane quantum circuit (all lanes valid; 8 lanes/row redundant) ----
        float d0 = a[0][0] + pb0;
        float d1 = a[0][1] + pb1;
        float d2 = a[0][2] + pb2;

        float t0 = tanhf(d0) * 0.785398163397448f;
        float t1 = tanhf(d1) * 0.785398163397448f;
        float t2 = tanhf(d2) * 0.785398163397448f;
        float s0 = sinf(t0), c0 = cosf(t0);
        float s1 = sinf(t1), c1 = cosf(t1);
        float s2 = sinf(t2), c2 = cosf(t2);

        const float r8 = 0.353553390593274f;
        float u0m = c0 - s0, u0p = c0 + s0;
        float u1m = c1 - s1, u1p = c1 + s1;
        float u2m = (c2 - s2) * r8, u2p = (c2 + s2) * r8;
        float t00 = u0m * u1m, t01 = u0m * u1p, t10 = u0p * u1m, t11 = u0p * u1p;
        float q0 = t00 * u2m, q1 = t00 * u2p;   // idx = 4*b0 + 2*b1 + b2
        float q2 = t01 * u2m, q3 = t01 * u2p;
        float q4 = t10 * u2m, q5 = t10 * u2p;
        float q6 = t11 * u2m, q7 = t11 * u2p;

        #pragma unroll
        for (int k = 0; k < 2; ++k) {
            SWAPF(q4, q6); SWAPF(q5, q7);       // CNOT(q0 -> q1)
            SWAPF(q2, q3); SWAPF(q6, q7);       // CNOT(q1 -> q2)
            float c = cw[k][0], s = sw[k][0];   // RY qubit 0: pairs (i, i+4)
            RYPAIR(q0, q4, c, s); RYPAIR(q1, q5, c, s); RYPAIR(q2, q6, c, s); RYPAIR(q3, q7, c, s);
            c = cw[k][1]; s = sw[k][1];         // RY qubit 1: pairs (i, i+2)
            RYPAIR(q0, q2, c, s); RYPAIR(q1, q3, c, s); RYPAIR(q4, q6, c, s); RYPAIR(q5, q7, c, s);
            c = cw[k][2]; s = sw[k][2];         // RY qubit 2: pairs (i, i+1)
            RYPAIR(q0, q1, c, s); RYPAIR(q2, q3, c, s); RYPAIR(q4, q5, c, s); RYPAIR(q6, q7, c, s);
        }

        float p0 = q0 * q0, p1 = q1 * q1, p2 = q2 * q2, p3 = q3 * q3;
        float p4 = q4 * q4, p5 = q5 * q5, p6 = q6 * q6, p7 = q7 * q7;
        float s01 = p0 + p1, s23 = p2 + p3, s45 = p4 + p5, s67 = p6 + p7;
        float z0 = (s01 + s23) - (s45 + s67);
        float z1 = (s01 - s23) + (s45 - s67);
        float z2 = (p0 - p1) + ((p2 - p3) + ((p4 - p5) + (p6 - p7)));

        // ---- Phase C: epilogue GEMM [*,3]x[3,100] + coalesced f32 stores.
        //      Row s lives in lanes [8s..8s+7]; __shfl(., 8s) is v_readlane. ----
        #pragma unroll
        for (int s = 0; s < TILE; ++s) {
            float zz0 = __shfl(z0, 8 * s);
            float zz1 = __shfl(z1, 8 * s);
            float zz2 = __shfl(z2, 8 * s);
            int row = tile_base + s;
            float v0 = fmaf(zz2, w02, fmaf(zz1, w01, fmaf(zz0, w00, b0)));
            float v1 = fmaf(zz2, w12, fmaf(zz1, w11, fmaf(zz0, w10, b1)));
            if (lane < 50 && row < B) {
                vf2 st; st.x = v0; st.y = v1;
                vf2* op = (vf2*)(out + (size_t)row * 50 + lane);
                __builtin_nontemporal_store(st, op);   // 50 lanes x 8B = 400B/row contiguous
            }
        }
    }
}

extern "C" void kernel_launch(void* const* d_in, const int* in_sizes, int n_in,
                              void* d_out, int out_size, void* d_ws, size_t ws_size,
                              hipStream_t stream) {
    const float4* in4   = (const float4*)d_in[0];
    const float4* preW4 = (const float4*)d_in[1];
    const float*  preb  = (const float*)d_in[2];
    const float*  qp    = (const float*)d_in[3];
    const float*  postW = (const float*)d_in[4];
    const float*  postb = (const float*)d_in[5];
    float2*       out   = (float2*)d_out;

    int B = in_sizes[0] / FDIM;                    // 65536
    int maxblocks = (B + SPB - 1) / SPB;           // 2048 at B=65536
    int nblocks = maxblocks < NBLK ? maxblocks : NBLK;   // 1024 -> 2 tiles/wave
    qnet_v4<<<nblocks, 256, 0, stream>>>(in4, preW4, preb, qp, postW, postb, out, B);
}

// Round 4
// 197.453 us; speedup vs baseline: 1.0643x; 1.0123x over previous
//
#include <hip/hip_runtime.h>
#include <math.h>

#define FDIM 512
#define TILE 8                  // rows per wave
#define WPB  4                  // waves per block
#define SPB  (TILE * WPB)       // 32 rows per block
#define NBLK 768                // 3 blocks/CU at ~150 VGPR -> exactly resident

typedef float vf4 __attribute__((ext_vector_type(4)));
typedef float vf2 __attribute__((ext_vector_type(2)));

#define RYPAIR(x, y, c, s) { float n0_ = (c)*(x) - (s)*(y); float n1_ = (s)*(x) + (c)*(y); (x) = n0_; (y) = n1_; }
#define SWAPF(x, y) { float t_ = (x); (x) = (y); (y) = t_; }

// Merge-reduce two accumulators across lane-xor `mask`: lane keeps x's or y's
// reduction depending on (lane & mask); row index accumulates in high lane bits.
#define MERGE(x, y, mask) {                       \
    const bool hi_ = (lane & (mask));             \
    float keep_ = hi_ ? (y) : (x);                \
    float send_ = hi_ ? (x) : (y);                \
    (x) = keep_ + __shfl_xor(send_, (mask)); }

// Issue 8 coalesced 1KB wave-loads for rows [baserow, baserow+4).
#define LOADH(baserow, D0, D1) {                                              \
    _Pragma("unroll")                                                         \
    for (int s_ = 0; s_ < 4; ++s_) {                                          \
        const vf4* rp_ = (const vf4*)(in4 + (size_t)((baserow) + s_) * 128);  \
        D0[s_] = __builtin_nontemporal_load(rp_ + lane);                      \
        D1[s_] = __builtin_nontemporal_load(rp_ + 64 + lane);                 \
    } }

// Dot 4 rows against the 3 register-resident W rows -> a[off+s][0..2].
#define FMA4(D0, D1, off) {                                                                 \
    _Pragma("unroll")                                                                       \
    for (int s_ = 0; s_ < 4; ++s_) {                                                        \
        const vf4 i0 = D0[s_], i1 = D1[s_];                                                 \
        float a0 = fmaf(i0.w, w0a.w, fmaf(i0.z, w0a.z, fmaf(i0.y, w0a.y, i0.x * w0a.x)));   \
        a0 = fmaf(i1.w, w0b.w, fmaf(i1.z, w0b.z, fmaf(i1.y, w0b.y, fmaf(i1.x, w0b.x, a0))));\
        float a1 = fmaf(i0.w, w1a.w, fmaf(i0.z, w1a.z, fmaf(i0.y, w1a.y, i0.x * w1a.x)));   \
        a1 = fmaf(i1.w, w1b.w, fmaf(i1.z, w1b.z, fmaf(i1.y, w1b.y, fmaf(i1.x, w1b.x, a1))));\
        float a2 = fmaf(i0.w, w2a.w, fmaf(i0.z, w2a.z, fmaf(i0.y, w2a.y, i0.x * w2a.x)));   \
        a2 = fmaf(i1.w, w2b.w, fmaf(i1.z, w2b.z, fmaf(i1.y, w2b.y, fmaf(i1.x, w2b.x, a2))));\
        a[(off) + s_][0] = a0; a[(off) + s_][1] = a1; a[(off) + s_][2] = a2;                \
    } }

__global__ __launch_bounds__(256) void qnet_v5(
    const float4* __restrict__ in4,      // [B,512] f32, 128 float4 per row
    const float4* __restrict__ preW4,    // [3,512] f32 as 384 float4
    const float*  __restrict__ preb,     // [3] f32
    const float*  __restrict__ qp,       // [45] f32
    const float*  __restrict__ postW,    // [100,3] f32
    const float*  __restrict__ postb,    // [100] f32
    float2*       __restrict__ out,      // [B,100] f32 as [B,50] float2
    int B)
{
    const int tid  = threadIdx.x;
    const int lane = tid & 63;
    const int wave = tid >> 6;

    // ---- per-wave setup (amortized over ~2.7 tiles) ----
    const float4 w0a = preW4[lane],       w0b = preW4[64 + lane];
    const float4 w1a = preW4[128 + lane], w1b = preW4[192 + lane];
    const float4 w2a = preW4[256 + lane], w2b = preW4[320 + lane];

    const float pb0 = preb[0], pb1 = preb[1], pb2 = preb[2];

    float cw[2][3], sw[2][3];              // shared-weight RY half-angles (qw rows 1..2)
    #pragma unroll
    for (int k = 0; k < 2; ++k)
        #pragma unroll
        for (int j = 0; j < 3; ++j) {
            float th = 0.5f * qp[(k + 1) * 3 + j];
            sw[k][j] = sinf(th);
            cw[k][j] = cosf(th);
        }

    // epilogue weights: lane l (<50) produces outputs o=2l, 2l+1
    const int ol = (lane < 50) ? lane : 49;
    const float* pw = postW + 6 * ol;
    const float w00 = pw[0], w01 = pw[1], w02 = pw[2];
    const float w10 = pw[3], w11 = pw[4], w12 = pw[5];
    const float b0 = postb[2 * ol], b1 = postb[2 * ol + 1];

    const int stride = SPB * gridDim.x;          // rows covered per grid step
    int tb = blockIdx.x * SPB + wave * TILE;     // this wave's first tile base
    if (tb >= B) return;

    // ---- software pipeline: one 8-load (8KB) batch in flight at ALL times,
    //      including through the A2/B/C tail (next tile's half0 covers it). ----
    vf4 X0[4], X1[4];                            // half0 data (rows 0..3 of tile)
    vf4 Y0[4], Y1[4];                            // half1 data (rows 4..7 of tile)
    LOADH(tb, X0, X1);                           // prologue: tile0 half0

    #pragma unroll 1
    for (;;) {
        float a[TILE][3];
        LOADH(tb + 4, Y0, Y1);                   // issue half1 (8 loads in flight)
        FMA4(X0, X1, 0);                         // consume half0 (waits on X only)
        const int tbn = tb + stride;
        if (tbn < B) LOADH(tbn, X0, X1);         // issue next tile's half0 (uniform branch)
        FMA4(Y0, Y1, 4);                         // consume half1

        // ---- Phase A2: halving merge-reduction, 30 shfl total.
        //      Lane l ends carrying row (l>>3)'s full (d0,d1,d2). ----
        #pragma unroll
        for (int s = 0; s < 4; ++s) {
            #pragma unroll
            for (int j = 0; j < 3; ++j) MERGE(a[s][j], a[s + 4][j], 32);
        }
        #pragma unroll
        for (int s = 0; s < 2; ++s) {
            #pragma unroll
            for (int j = 0; j < 3; ++j) MERGE(a[s][j], a[s + 2][j], 16);
        }
        #pragma unroll
        for (int j = 0; j < 3; ++j) MERGE(a[0][j], a[1][j], 8);
        #pragma unroll
        for (int m = 4; m >= 1; m >>= 1) {
            #pragma unroll
            for (int j = 0; j < 3; ++j) a[0][j] += __shfl_xor(a[0][j], m);
        }

        // ---- Phase B: per-lane quantum circuit (8 lanes/row redundant).
        //      __sinf/__cosf -> v_sin/v_cos; args in [-pi/4,pi/4], err ~1e-6
        //      vs 1.6e-2 tolerance. Shrinks the load-silent tail. ----
        float d0 = a[0][0] + pb0;
        float d1 = a[0][1] + pb1;
        float d2 = a[0][2] + pb2;

        float t0 = tanhf(d0) * 0.785398163397448f;
        float t1 = tanhf(d1) * 0.785398163397448f;
        float t2 = tanhf(d2) * 0.785398163397448f;
        float s0 = __sinf(t0), c0 = __cosf(t0);
        float s1 = __sinf(t1), c1 = __cosf(t1);
        float s2 = __sinf(t2), c2 = __cosf(t2);

        const float r8 = 0.353553390593274f;
        float u0m = c0 - s0, u0p = c0 + s0;
        float u1m = c1 - s1, u1p = c1 + s1;
        float u2m = (c2 - s2) * r8, u2p = (c2 + s2) * r8;
        float t00 = u0m * u1m, t01 = u0m * u1p, t10 = u0p * u1m, t11 = u0p * u1p;
        float q0 = t00 * u2m, q1 = t00 * u2p;   // idx = 4*b0 + 2*b1 + b2
        float q2 = t01 * u2m, q3 = t01 * u2p;
        float q4 = t10 * u2m, q5 = t10 * u2p;
        float q6 = t11 * u2m, q7 = t11 * u2p;

        #pragma unroll
        for (int k = 0; k < 2; ++k) {
            SWAPF(q4, q6); SWAPF(q5, q7);       // CNOT(q0 -> q1)
            SWAPF(q2, q3); SWAPF(q6, q7);       // CNOT(q1 -> q2)
            float c = cw[k][0], s = sw[k][0];   // RY qubit 0: pairs (i, i+4)
            RYPAIR(q0, q4, c, s); RYPAIR(q1, q5, c, s); RYPAIR(q2, q6, c, s); RYPAIR(q3, q7, c, s);
            c = cw[k][1]; s = sw[k][1];         // RY qubit 1: pairs (i, i+2)
            RYPAIR(q0, q2, c, s); RYPAIR(q1, q3, c, s); RYPAIR(q4, q6, c, s); RYPAIR(q5, q7, c, s);
            c = cw[k][2]; s = sw[k][2];         // RY qubit 2: pairs (i, i+1)
            RYPAIR(q0, q1, c, s); RYPAIR(q2, q3, c, s); RYPAIR(q4, q5, c, s); RYPAIR(q6, q7, c, s);
        }

        float p0 = q0 * q0, p1 = q1 * q1, p2 = q2 * q2, p3 = q3 * q3;
        float p4 = q4 * q4, p5 = q5 * q5, p6 = q6 * q6, p7 = q7 * q7;
        float s01 = p0 + p1, s23 = p2 + p3, s45 = p4 + p5, s67 = p6 + p7;
        float z0 = (s01 + s23) - (s45 + s67);
        float z1 = (s01 - s23) + (s45 - s67);
        float z2 = (p0 - p1) + ((p2 - p3) + ((p4 - p5) + (p6 - p7)));

        // ---- Phase C: epilogue GEMM [*,3]x[3,100] + coalesced stores.
        //      Row s lives in lanes [8s..8s+7]; __shfl(., 8s) is v_readlane. ----
        #pragma unroll
        for (int s = 0; s < TILE; ++s) {
            float zz0 = __shfl(z0, 8 * s);
            float zz1 = __shfl(z1, 8 * s);
            float zz2 = __shfl(z2, 8 * s);
            int row = tb + s;
            float v0 = fmaf(zz2, w02, fmaf(zz1, w01, fmaf(zz0, w00, b0)));
            float v1 = fmaf(zz2, w12, fmaf(zz1, w11, fmaf(zz0, w10, b1)));
            if (lane < 50 && row < B) {
                vf2 st; st.x = v0; st.y = v1;
                vf2* op = (vf2*)(out + (size_t)row * 50 + lane);
                __builtin_nontemporal_store(st, op);   // 50 lanes x 8B = 400B/row
            }
        }

        if (tbn >= B) break;
        tb = tbn;
    }
}

extern "C" void kernel_launch(void* const* d_in, const int* in_sizes, int n_in,
                              void* d_out, int out_size, void* d_ws, size_t ws_size,
                              hipStream_t stream) {
    const float4* in4   = (const float4*)d_in[0];
    const float4* preW4 = (const float4*)d_in[1];
    const float*  preb  = (const float*)d_in[2];
    const float*  qp    = (const float*)d_in[3];
    const float*  postW = (const float*)d_in[4];
    const float*  postb = (const float*)d_in[5];
    float2*       out   = (float2*)d_out;

    int B = in_sizes[0] / FDIM;                    // 65536
    int maxblocks = (B + SPB - 1) / SPB;           // 2048 at B=65536
    int nblocks = maxblocks < NBLK ? maxblocks : NBLK;   // 768 -> ~2.7 tiles/wave
    qnet_v5<<<nblocks, 256, 0, stream>>>(in4, preW4, preb, qp, postW, postb, out, B);
}